// Round 2
// baseline (105.124 us; speedup 1.0000x reference)
//
#include <hip/hip_runtime.h>

// MMD loss, class-compacted (r15). 3 nodes: memset(16KB), k_fused, k_pairs.
// r15 changes vs r14 (99.9us):
//  (1) k_pairs ns de-duplicated 8x -> 1x: grid (C, 1+WY). Block (c,0) is the
//      ns PRODUCER (computes ||sum x||^2 -> inv0, publishes ONE word via
//      agent-scope atomic store; inv0>0 always so 0 is the poison-safe
//      sentinel). Worker blocks (c,1..WY) run MFMA tiles immediately and
//      lazy-spin for inv0 only in the post-MFMA epilogue -> spin hides under
//      MFMA. Saves ~44MB L2/L3 re-reads. Deadlock-safe: 279 blocks, producers
//      are block ids 0..30 (dispatched first), capacity >= 256 blocks.
//      This is a one-way single-word publish, NOT the r9 grid barrier.
//  (2) Producer's 4 waves take tile slots 32..35 after publishing -> classes
//      with 36 tiles (n>224) no longer have 2-tile waves.
//  (3) k_fused: presence flags now unconditional plain stores (end-of-kernel
//      L2 writeback gives cross-kernel visibility; all writers store 1);
//      target argmax reduction starts at o=16 (values live in lanes 0..30).
//  (4) k_pairs: sq/sgn scalar loads hoisted before the MFMA loop.
// NOTE: top-5 rocprof dispatches are the harness's fixed 256MiB workspace
// poison fills (41us @81% HBM peak) - NOT controllable from kernel source.
// DO NOT reintroduce: r9 persistent grid-barrier (434us); r5 per-element
// colsum atomics (34MB writes); r2 per-block fences at 6144 grid; r12
// unpadded per-row atomics (54us k_fused); r13 shared rank/ssum/flag line;
// r13 per-block 31-class serial prefix scan.
// Math verified absmax 0.0 r1-r14: class bucketing, upper-tri tiles w/ 2x
// off-diag, m@D@m = 2n*sum(sq)-2*||sum x||^2, MFMA C/D map col=lane&31,
// row=(reg&3)+8*(reg>>2)+4*(lane>>5). Panel layout: class c base c*RCAP
// rows; 32-row panels; chunk m (cols m*8..m*8+7) of row i at
// panel*D + (m>>1)*512 + ((m&1)*32 + (i&31))*8.

#define CMAX 32
#define RCAP 6144      // fixed rows per class region (worst case N=6144)
#define PCW 32         // ints per padded counter line (128B)
#define WY 8           // worker blocks per class (y=1..WY); y=0 = ns producer

typedef __attribute__((ext_vector_type(8)))  short  short8;
typedef __attribute__((ext_vector_type(8)))  unsigned short ushort8;
typedef __attribute__((ext_vector_type(16))) float  float16;

__device__ inline unsigned short f2bf(float x) {  // fp32 -> bf16 RNE
  unsigned u = __float_as_uint(x);
  return (unsigned short)((u + 0x7FFFu + ((u >> 16) & 1u)) >> 16);
}

// ---- K1: wave-per-row single pass: label + rank + sq + bf16 panel write ----
// Counter layout (all padded to one 128B line per class, SEPARATE regions):
//   pc[c*PCW]              rank counter (row allocation)
//   pc[(CMAX+c)*PCW]       float ssum (sum of row sq-norms)
//   pc[(2*CMAX+c)*PCW]+0/1 src/tgt presence flags (plain stores, value 1)
__global__ __launch_bounds__(256) void k_fused(
    const float* __restrict__ src, const float* __restrict__ tgt,
    const int* __restrict__ slab, const float* __restrict__ tlabel,
    const int* __restrict__ nsd_p,
    int* pc,
    unsigned short* __restrict__ fragbuf,
    float* __restrict__ sqc, float* __restrict__ sgnc,
    int S_total, int T, int D, int C) {
  int lane = threadIdx.x & 63;
  int gwid = (blockIdx.x * 256 + threadIdx.x) >> 6;
  int nwv = (gridDim.x * 256) >> 6;
  int nsd = nsd_p[0];
  int S_use = S_total - nsd;
  int N = S_use + T;

  for (int r = gwid; r < N; r += nwv) {
    int c;
    const float* row;
    bool isSrc = (r < S_use);
    if (isSrc) {
      c = slab[nsd + r];
      row = src + (size_t)(nsd + r) * D;
    } else {
      int t = r - S_use;
      row = tgt + (size_t)t * D;
      float v = (lane < C) ? tlabel[(size_t)t * C + lane] : -3.4e38f;
      int idx = lane;
      for (int o = 16; o > 0; o >>= 1) {   // values only in lanes 0..30
        float ov = __shfl_down(v, o, 64);
        int oi = __shfl_down(idx, o, 64);
        if (ov > v || (ov == v && oi < idx)) { v = ov; idx = oi; }
      }
      c = __shfl(idx, 0, 64);
    }
    const float4* s4 = (const float4*)row;
    int nm = D >> 3;
    float4 v0, v1;
    if (lane < nm) { v0 = s4[lane * 2]; v1 = s4[lane * 2 + 1]; }  // in flight

    int rk;
    if (lane == 0) rk = atomicAdd(&pc[c * PCW], 1);   // own 128B line/class
    rk = __shfl(rk, 0, 64);
    int p = c * RCAP + rk;
    unsigned short* pb = fragbuf + (size_t)(c * RCAP + (rk & ~31)) * D;
    int row32 = rk & 31;

    float s = 0.f;
    if (lane < nm) {
      s += v0.x * v0.x + v0.y * v0.y + v0.z * v0.z + v0.w * v0.w +
           v1.x * v1.x + v1.y * v1.y + v1.z * v1.z + v1.w * v1.w;
      ushort8 h;
      h[0] = f2bf(v0.x); h[1] = f2bf(v0.y); h[2] = f2bf(v0.z); h[3] = f2bf(v0.w);
      h[4] = f2bf(v1.x); h[5] = f2bf(v1.y); h[6] = f2bf(v1.z); h[7] = f2bf(v1.w);
      int st = lane >> 1, hf = lane & 1;
      *(ushort8*)(pb + st * 512 + (hf * 32 + row32) * 8) = h;
    }
    for (int m = lane + 64; m < nm; m += 64) {   // D>512 fallback (not hit)
      float4 w0 = s4[m * 2], w1 = s4[m * 2 + 1];
      s += w0.x * w0.x + w0.y * w0.y + w0.z * w0.z + w0.w * w0.w +
           w1.x * w1.x + w1.y * w1.y + w1.z * w1.z + w1.w * w1.w;
      ushort8 h;
      h[0] = f2bf(w0.x); h[1] = f2bf(w0.y); h[2] = f2bf(w0.z); h[3] = f2bf(w0.w);
      h[4] = f2bf(w1.x); h[5] = f2bf(w1.y); h[6] = f2bf(w1.z); h[7] = f2bf(w1.w);
      int st = m >> 1, hf = m & 1;
      *(ushort8*)(pb + st * 512 + (hf * 32 + row32) * 8) = h;
    }
    for (int o = 32; o > 0; o >>= 1) s += __shfl_down(s, o, 64);
    if (lane == 0) {
      sqc[p] = s;
      sgnc[p] = isSrc ? 1.f : -1.f;
      atomicAdd((float*)&pc[(CMAX + c) * PCW], s);            // own line
      pc[(2 * CMAX + c) * PCW + (isSrc ? 0 : 1)] = 1;          // plain store
    }
  }
}

// ---- K2: grid (C, 1+WY). y==0: ns producer (+tile slots 32..35);
//      y>=1: MFMA tiles with lazy inv0 acquire in the epilogue + final fold --
__global__ __launch_bounds__(256) void k_pairs(
    const unsigned short* __restrict__ fragbuf, const float* __restrict__ sqc,
    const float* __restrict__ sgnc, const int* __restrict__ pc,
    int* bws, float* losssum, int* done, float* __restrict__ out,
    int D, int C) {
  __shared__ float scs[4][64][8];
  __shared__ int lastFlag;
  int c = blockIdx.x, y = blockIdx.y;
  int tid = threadIdx.x;
  int n = pc[c * PCW];
  int off = c * RCAP;
  const unsigned short* base = fragbuf + (size_t)off * D;
  int nm = D >> 3;

  if (y == 0) {
    // ns = ||sum_i x_i||^2 from bf16 panels. Thread owns chunk cl (cols
    // cl*8..cl*8+7) for rows i == rg (mod 4); coalesced 16B loads.
    int rg = tid >> 6, cl = tid & 63;
    float nspart = 0.f;
    for (int m0 = 0; m0 < nm; m0 += 64) {     // one pass at D=512
      int m = m0 + cl;
      float cs[8] = {0.f, 0.f, 0.f, 0.f, 0.f, 0.f, 0.f, 0.f};
      if (m < nm) {
        int st = m >> 1, hf = m & 1;
        for (int i = rg; i < n; i += 4) {
          ushort8 v = *(const ushort8*)(base + (size_t)(i & ~31) * D +
                                        st * 512 + (hf * 32 + (i & 31)) * 8);
          #pragma unroll
          for (int j = 0; j < 8; j++)
            cs[j] += __uint_as_float((unsigned)v[j] << 16);
        }
      }
      #pragma unroll
      for (int j = 0; j < 8; j++) scs[rg][cl][j] = cs[j];
      __syncthreads();
      if (tid < 64) {
        #pragma unroll
        for (int j = 0; j < 8; j++) {
          float t = scs[0][tid][j] + scs[1][tid][j] +
                    scs[2][tid][j] + scs[3][tid][j];
          nspart += t * t;
        }
      }
      __syncthreads();
    }
    if (tid < 64) {
      for (int o = 32; o > 0; o >>= 1) nspart += __shfl_down(nspart, o, 64);
      if (tid == 0) {
        float ss = ((const float*)pc)[(CMAX + c) * PCW];
        float nf = (float)n;
        float S1 = 2.f * nf * ss - 2.f * nspart;   // == m @ Dmat @ m
        float bw = S1 / fmaxf(nf * nf - nf, 1.f);
        bw = (bw > 0.f) ? bw : 1.f;
        float inv0 = 4.f / bw;                     // 1/(bw*0.25), always > 0
        __hip_atomic_store(bws + c * PCW, __float_as_int(inv0),
                           __ATOMIC_RELEASE, __HIP_MEMORY_SCOPE_AGENT);
      }
    }
    // producer waves fall through to tile slots 32..35 (lazy-load own slot)
  }

  int tpr = (n + 31) >> 5;
  int tiles = tpr * (tpr + 1) / 2;
  int lane = tid & 63, l31 = lane & 31, half = lane >> 5;
  int wvc = (y == 0) ? (4 * WY + (tid >> 6)) : ((y - 1) * 4 + (tid >> 6));
  int nwvc = 4 * WY + 4;   // 36 slots: all waves <=1 tile up to tpr=8
  float inv0 = -1.f;       // sentinel: not yet acquired
  float wsum = 0.f;

  for (int t = wvc; t < tiles; t += nwvc) {
    int lt = t, jt = 0;
    while (lt >= tpr - jt) { lt -= tpr - jt; jt++; }
    int kt = jt + lt;
    int jbase = jt << 5, kbase = kt << 5;
    float wgt = (jt == kt) ? 1.f : 2.f;

    float sqk  = sqc[off + kbase + l31];           // hoisted: hide under MFMA
    float sgk  = sgnc[off + kbase + l31];
    float sqjv = sqc[off + jbase + l31];
    float sgjv = sgnc[off + jbase + l31];
    bool kval = (kbase + l31) < n;

    const unsigned short* fa  = fragbuf + (size_t)(off + jbase) * D + lane * 8;
    const unsigned short* fbp = fragbuf + (size_t)(off + kbase) * D + lane * 8;
    float16 acc = {};
    if (D == 512) {
      #pragma unroll
      for (int s = 0; s < 32; s++) {
        short8 a = *(const short8*)(fa + s * 512);
        short8 b = *(const short8*)(fbp + s * 512);
        acc = __builtin_amdgcn_mfma_f32_32x32x16_bf16(a, b, acc, 0, 0, 0);
      }
    } else {
      for (int s = 0; s < (D >> 4); s++) {
        short8 a = *(const short8*)(fa + s * 512);
        short8 b = *(const short8*)(fbp + s * 512);
        acc = __builtin_amdgcn_mfma_f32_32x32x16_bf16(a, b, acc, 0, 0, 0);
      }
    }

    if (inv0 < 0.f) {        // lazy acquire: producer done by now (~0 spin)
      int v;
      if (lane == 0) {
        v = __hip_atomic_load(bws + c * PCW, __ATOMIC_ACQUIRE,
                              __HIP_MEMORY_SCOPE_AGENT);
        while (v == 0) {
          __builtin_amdgcn_s_sleep(2);
          v = __hip_atomic_load(bws + c * PCW, __ATOMIC_ACQUIRE,
                                __HIP_MEMORY_SCOPE_AGENT);
        }
      }
      v = __shfl(v, 0, 64);
      inv0 = __int_as_float(v);
    }

    float contrib = 0.f;
    #pragma unroll
    for (int r = 0; r < 16; r++) {
      int m = (r & 3) + 8 * (r >> 2) + 4 * half;
      float sqj = __shfl(sqjv, m, 64);
      float sgj = __shfl(sgjv, m, 64);
      if (kval && (jbase + m) < n) {
        float d = fmaxf(sqj + sqk - 2.f * acc[r], 0.f);
        float s = inv0, kv = 0.f;
        #pragma unroll
        for (int q = 0; q < 5; q++) { kv += __expf(-d * s); s *= 0.5f; }
        contrib += sgj * sgk * kv;
      }
    }
    wsum += wgt * contrib;
  }
  for (int o = 32; o > 0; o >>= 1) wsum += __shfl_down(wsum, o, 64);
  if (lane == 0 && wsum != 0.f) atomicAdd(&losssum[c], wsum);

  // last-block fold -> final scalar (one fence+atomic per BLOCK)
  __syncthreads();
  if (tid == 0) {
    __threadfence();
    int d = atomicAdd(done, 1);
    lastFlag = (d == (int)(gridDim.x * gridDim.y) - 1);
  }
  __syncthreads();
  if (lastFlag && tid < 64) {
    int cc = tid;
    float loss = 0.f, cv = 0.f;
    if (cc < C && pc[(2 * CMAX + cc) * PCW] > 0 &&
        pc[(2 * CMAX + cc) * PCW + 1] > 0) {
      float nf = (float)pc[cc * PCW];
      loss = atomicAdd(&losssum[cc], 0.f) / fmaxf(nf * nf, 1.f);  // coherent
      cv = 1.f;
    }
    for (int o = 32; o > 0; o >>= 1) {
      loss += __shfl_down(loss, o, 64);
      cv   += __shfl_down(cv, o, 64);
    }
    if (tid == 0) out[0] = loss / fmaxf(cv, 1.f);
  }
}

extern "C" void kernel_launch(void* const* d_in, const int* in_sizes, int n_in,
                              void* d_out, int out_size, void* d_ws, size_t ws_size,
                              hipStream_t stream) {
  const float* source = (const float*)d_in[0];
  const float* target = (const float*)d_in[1];
  const int* slab     = (const int*)d_in[2];
  const float* tlabel = (const float*)d_in[3];
  const int* nsd_p    = (const int*)d_in[4];
  float* out = (float*)d_out;

  int S_total = in_sizes[2];
  int D = in_sizes[0] / S_total;   // 512
  int T = in_sizes[1] / D;         // 2048
  int C = in_sizes[3] / T;         // 31

  // workspace layout (4-byte words); zeroed-by-memset region first (~16.5KB)
  int* ws = (int*)d_ws;
  int* pc       = ws;                               // 3*CMAX*PCW padded lines
  int* bws      = ws + 3 * CMAX * PCW;              // CMAX*PCW (inv0 slots)
  float* losssum = (float*)(ws + 4 * CMAX * PCW);   // C
  int* done     = (int*)(losssum + C);              // 8
  int zwords    = 4 * CMAX * PCW + C + 8;

  float* sqc    = (float*)(ws + zwords);            // C*RCAP
  float* sgnc   = sqc + (size_t)C * RCAP;           // C*RCAP
  size_t words_used = (size_t)zwords + 2 * (size_t)C * RCAP;
  size_t fw = (words_used + 63) & ~(size_t)63;      // 256B-align fragbuf
  unsigned short* fragbuf = (unsigned short*)(ws + fw);  // C*RCAP*D bf16

  hipMemsetAsync(d_ws, 0, (size_t)zwords * sizeof(int), stream);

  k_fused<<<1024, 256, 0, stream>>>(source, target, slab, tlabel, nsd_p,
                                    pc, fragbuf, sqc, sgnc,
                                    S_total, T, D, C);
  k_pairs<<<dim3(C, 1 + WY), 256, 0, stream>>>(fragbuf, sqc, sgnc, pc,
                                               bws, losssum, done, out, D, C);
}

// Round 3
// 95.656 us; speedup vs baseline: 1.0990x; 1.0990x over previous
//
#include <hip/hip_runtime.h>

// MMD loss, class-compacted (r16). 3 nodes: memset(12KB), k_fused, k_pairs.
// r16 = r14 structure + PAIR_Y 8->4. r15's producer/consumer ns publish
// REGRESSED +5.2us (99.9->105.1): single-word cross-XCD publish + worker
// acquire-spin costs more than 8x redundant fully-parallel panel reads.
// DO NOT reintroduce cross-block inv0 publish/spin.
// r16 rationale: with n~132/class, tiles = 15 (tpr=5). PAIR_Y=8 gave 32
// wave-slots/class -> blocks y=4..7 had ZERO tiles yet still ran the full ns
// phase (re-reading ~132KB panel each). PAIR_Y=4 keeps 16 slots >= 15 tiles,
// halves ns traffic + block count with NO sync change.
// Kept from r15 (harmless micros): argmax reduce from o=16 (31 lanes live),
// sq/sgn hoisted before MFMA loop, per-wave wsum + single atomic (was
// per-tile). Reverted to volatile-check+atomicExch flags (r15 plain stores
// to 2 words of one line from different XCDs risk lost-update on L2
// writeback).
// NOTE: top-5 rocprof dispatches are the harness's fixed 256MiB workspace
// poison fills (41us @82% HBM peak) - NOT controllable from kernel source.
// DO NOT reintroduce: r9 persistent grid-barrier (434us); r5 per-element
// colsum atomics (34MB writes); r2 per-block fences at 6144 grid; r12
// unpadded per-row atomics (54us k_fused); r13 shared rank/ssum/flag line;
// r13 per-block 31-class serial prefix scan; r15 ns producer/consumer spin.
// Math verified absmax 0.0 r1-r15: class bucketing, upper-tri tiles w/ 2x
// off-diag, m@D@m = 2n*sum(sq)-2*||sum x||^2, MFMA C/D map col=lane&31,
// row=(reg&3)+8*(reg>>2)+4*(lane>>5). Panel layout: class c base c*RCAP
// rows; 32-row panels; chunk m (cols m*8..m*8+7) of row i at
// panel*D + (m>>1)*512 + ((m&1)*32 + (i&31))*8.

#define CMAX 32
#define RCAP 6144      // fixed rows per class region (worst case N=6144)
#define PCW 32         // ints per padded counter line (128B)
#define PAIR_Y 4       // blocks per class in k_pairs (16 wave slots >= 15 tiles)

typedef __attribute__((ext_vector_type(8)))  short  short8;
typedef __attribute__((ext_vector_type(8)))  unsigned short ushort8;
typedef __attribute__((ext_vector_type(16))) float  float16;

__device__ inline unsigned short f2bf(float x) {  // fp32 -> bf16 RNE
  unsigned u = __float_as_uint(x);
  return (unsigned short)((u + 0x7FFFu + ((u >> 16) & 1u)) >> 16);
}

// ---- K1: wave-per-row single pass: label + rank + sq + bf16 panel write ----
// Counter layout (all padded to one 128B line per class, SEPARATE regions):
//   pc[c*PCW]              rank counter (row allocation)
//   pc[(CMAX+c)*PCW]       float ssum (sum of row sq-norms)
//   pc[(2*CMAX+c)*PCW]+0/1 src/tgt presence flags (volatile check + exch)
__global__ __launch_bounds__(256) void k_fused(
    const float* __restrict__ src, const float* __restrict__ tgt,
    const int* __restrict__ slab, const float* __restrict__ tlabel,
    const int* __restrict__ nsd_p,
    int* pc,
    unsigned short* __restrict__ fragbuf,
    float* __restrict__ sqc, float* __restrict__ sgnc,
    int S_total, int T, int D, int C) {
  int lane = threadIdx.x & 63;
  int gwid = (blockIdx.x * 256 + threadIdx.x) >> 6;
  int nwv = (gridDim.x * 256) >> 6;
  int nsd = nsd_p[0];
  int S_use = S_total - nsd;
  int N = S_use + T;

  for (int r = gwid; r < N; r += nwv) {
    int c;
    const float* row;
    bool isSrc = (r < S_use);
    if (isSrc) {
      c = slab[nsd + r];
      row = src + (size_t)(nsd + r) * D;
    } else {
      int t = r - S_use;
      row = tgt + (size_t)t * D;
      float v = (lane < C) ? tlabel[(size_t)t * C + lane] : -3.4e38f;
      int idx = lane;
      for (int o = 16; o > 0; o >>= 1) {   // values only in lanes 0..30
        float ov = __shfl_down(v, o, 64);
        int oi = __shfl_down(idx, o, 64);
        if (ov > v || (ov == v && oi < idx)) { v = ov; idx = oi; }
      }
      c = __shfl(idx, 0, 64);
    }
    const float4* s4 = (const float4*)row;
    int nm = D >> 3;
    float4 v0, v1;
    if (lane < nm) { v0 = s4[lane * 2]; v1 = s4[lane * 2 + 1]; }  // in flight

    int rk;
    if (lane == 0) rk = atomicAdd(&pc[c * PCW], 1);   // own 128B line/class
    rk = __shfl(rk, 0, 64);
    int p = c * RCAP + rk;
    unsigned short* pb = fragbuf + (size_t)(c * RCAP + (rk & ~31)) * D;
    int row32 = rk & 31;

    float s = 0.f;
    if (lane < nm) {
      s += v0.x * v0.x + v0.y * v0.y + v0.z * v0.z + v0.w * v0.w +
           v1.x * v1.x + v1.y * v1.y + v1.z * v1.z + v1.w * v1.w;
      ushort8 h;
      h[0] = f2bf(v0.x); h[1] = f2bf(v0.y); h[2] = f2bf(v0.z); h[3] = f2bf(v0.w);
      h[4] = f2bf(v1.x); h[5] = f2bf(v1.y); h[6] = f2bf(v1.z); h[7] = f2bf(v1.w);
      int st = lane >> 1, hf = lane & 1;
      *(ushort8*)(pb + st * 512 + (hf * 32 + row32) * 8) = h;
    }
    for (int m = lane + 64; m < nm; m += 64) {   // D>512 fallback (not hit)
      float4 w0 = s4[m * 2], w1 = s4[m * 2 + 1];
      s += w0.x * w0.x + w0.y * w0.y + w0.z * w0.z + w0.w * w0.w +
           w1.x * w1.x + w1.y * w1.y + w1.z * w1.z + w1.w * w1.w;
      ushort8 h;
      h[0] = f2bf(w0.x); h[1] = f2bf(w0.y); h[2] = f2bf(w0.z); h[3] = f2bf(w0.w);
      h[4] = f2bf(w1.x); h[5] = f2bf(w1.y); h[6] = f2bf(w1.z); h[7] = f2bf(w1.w);
      int st = m >> 1, hf = m & 1;
      *(ushort8*)(pb + st * 512 + (hf * 32 + row32) * 8) = h;
    }
    for (int o = 32; o > 0; o >>= 1) s += __shfl_down(s, o, 64);
    if (lane == 0) {
      sqc[p] = s;
      sgnc[p] = isSrc ? 1.f : -1.f;
      atomicAdd((float*)&pc[(CMAX + c) * PCW], s);            // own line
      int* flag = &pc[(2 * CMAX + c) * PCW + (isSrc ? 0 : 1)]; // own line
      if (*(volatile int*)flag == 0) atomicExch(flag, 1);      // set-once
    }
  }
}

// ---- K2: per-class ns+bw (once per block) + MFMA pair tiles + final fold ----
// grid (C, PAIR_Y): block (c,y) computes ns for class c cooperatively
// (coalesced ushort8 reads in panel write-order), bw once into LDS, then its
// 4 waves process tiles y*4+w, stride PAIR_Y*4.
__global__ __launch_bounds__(256) void k_pairs(
    const unsigned short* __restrict__ fragbuf, const float* __restrict__ sqc,
    const float* __restrict__ sgnc, const int* __restrict__ pc,
    float* losssum, int* done, float* __restrict__ out, int D, int C) {
  __shared__ float scs[4][64][8];
  __shared__ float s_inv0;
  __shared__ int lastFlag;
  int c = blockIdx.x;
  int tid = threadIdx.x;
  int n = pc[c * PCW];
  int off = c * RCAP;
  const unsigned short* base = fragbuf + (size_t)off * D;
  int nm = D >> 3;

  // ns = ||sum_i x_i||^2 from bf16 panels. Thread owns chunk cl (cols
  // cl*8..cl*8+7) for rows i == rg (mod 4); coalesced 16B loads.
  int rg = tid >> 6, cl = tid & 63;
  float nspart = 0.f;
  for (int m0 = 0; m0 < nm; m0 += 64) {     // one pass at D=512
    int m = m0 + cl;
    float cs[8] = {0.f, 0.f, 0.f, 0.f, 0.f, 0.f, 0.f, 0.f};
    if (m < nm) {
      int st = m >> 1, hf = m & 1;
      for (int i = rg; i < n; i += 4) {
        ushort8 v = *(const ushort8*)(base + (size_t)(i & ~31) * D +
                                      st * 512 + (hf * 32 + (i & 31)) * 8);
        #pragma unroll
        for (int j = 0; j < 8; j++)
          cs[j] += __uint_as_float((unsigned)v[j] << 16);
      }
    }
    #pragma unroll
    for (int j = 0; j < 8; j++) scs[rg][cl][j] = cs[j];
    __syncthreads();
    if (tid < 64) {
      #pragma unroll
      for (int j = 0; j < 8; j++) {
        float t = scs[0][tid][j] + scs[1][tid][j] +
                  scs[2][tid][j] + scs[3][tid][j];
        nspart += t * t;
      }
    }
    __syncthreads();
  }
  if (tid < 64) {
    for (int o = 32; o > 0; o >>= 1) nspart += __shfl_down(nspart, o, 64);
    if (tid == 0) {
      float ss = ((const float*)pc)[(CMAX + c) * PCW];
      float nf = (float)n;
      float S1 = 2.f * nf * ss - 2.f * nspart;   // == m @ Dmat @ m
      float bw = S1 / fmaxf(nf * nf - nf, 1.f);
      bw = (bw > 0.f) ? bw : 1.f;
      s_inv0 = 4.f / bw;                         // 1 / (bw * 0.25)
    }
  }
  __syncthreads();
  float inv0 = s_inv0;

  int tpr = (n + 31) >> 5;
  int tiles = tpr * (tpr + 1) / 2;
  int lane = tid & 63, l31 = lane & 31, half = lane >> 5;
  int wvc = blockIdx.y * 4 + (tid >> 6);
  int nwvc = gridDim.y * 4;    // 16 slots: all waves <=1 tile up to tpr=5
  float wsum = 0.f;

  for (int t = wvc; t < tiles; t += nwvc) {
    int lt = t, jt = 0;
    while (lt >= tpr - jt) { lt -= tpr - jt; jt++; }
    int kt = jt + lt;
    int jbase = jt << 5, kbase = kt << 5;
    float wgt = (jt == kt) ? 1.f : 2.f;

    float sqk  = sqc[off + kbase + l31];           // hoisted: hide under MFMA
    float sgk  = sgnc[off + kbase + l31];
    float sqjv = sqc[off + jbase + l31];
    float sgjv = sgnc[off + jbase + l31];
    bool kval = (kbase + l31) < n;

    const unsigned short* fa  = fragbuf + (size_t)(off + jbase) * D + lane * 8;
    const unsigned short* fbp = fragbuf + (size_t)(off + kbase) * D + lane * 8;
    float16 acc = {};
    if (D == 512) {
      #pragma unroll
      for (int s = 0; s < 32; s++) {
        short8 a = *(const short8*)(fa + s * 512);
        short8 b = *(const short8*)(fbp + s * 512);
        acc = __builtin_amdgcn_mfma_f32_32x32x16_bf16(a, b, acc, 0, 0, 0);
      }
    } else {
      for (int s = 0; s < (D >> 4); s++) {
        short8 a = *(const short8*)(fa + s * 512);
        short8 b = *(const short8*)(fbp + s * 512);
        acc = __builtin_amdgcn_mfma_f32_32x32x16_bf16(a, b, acc, 0, 0, 0);
      }
    }

    float contrib = 0.f;
    #pragma unroll
    for (int r = 0; r < 16; r++) {
      int m = (r & 3) + 8 * (r >> 2) + 4 * half;
      float sqj = __shfl(sqjv, m, 64);
      float sgj = __shfl(sgjv, m, 64);
      if (kval && (jbase + m) < n) {
        float d = fmaxf(sqj + sqk - 2.f * acc[r], 0.f);
        float s = inv0, kv = 0.f;
        #pragma unroll
        for (int q = 0; q < 5; q++) { kv += __expf(-d * s); s *= 0.5f; }
        contrib += sgj * sgk * kv;
      }
    }
    wsum += wgt * contrib;
  }
  for (int o = 32; o > 0; o >>= 1) wsum += __shfl_down(wsum, o, 64);
  if (lane == 0 && wsum != 0.f) atomicAdd(&losssum[c], wsum);

  // last-block fold -> final scalar (one fence+atomic per BLOCK)
  __syncthreads();
  if (tid == 0) {
    __threadfence();
    int d = atomicAdd(done, 1);
    lastFlag = (d == (int)(gridDim.x * gridDim.y) - 1);
  }
  __syncthreads();
  if (lastFlag && tid < 64) {
    int cc = tid;
    float loss = 0.f, cv = 0.f;
    if (cc < C && pc[(2 * CMAX + cc) * PCW] > 0 &&
        pc[(2 * CMAX + cc) * PCW + 1] > 0) {
      float nf = (float)pc[cc * PCW];
      loss = atomicAdd(&losssum[cc], 0.f) / fmaxf(nf * nf, 1.f);  // coherent
      cv = 1.f;
    }
    for (int o = 32; o > 0; o >>= 1) {
      loss += __shfl_down(loss, o, 64);
      cv   += __shfl_down(cv, o, 64);
    }
    if (tid == 0) out[0] = loss / fmaxf(cv, 1.f);
  }
}

extern "C" void kernel_launch(void* const* d_in, const int* in_sizes, int n_in,
                              void* d_out, int out_size, void* d_ws, size_t ws_size,
                              hipStream_t stream) {
  const float* source = (const float*)d_in[0];
  const float* target = (const float*)d_in[1];
  const int* slab     = (const int*)d_in[2];
  const float* tlabel = (const float*)d_in[3];
  const int* nsd_p    = (const int*)d_in[4];
  float* out = (float*)d_out;

  int S_total = in_sizes[2];
  int D = in_sizes[0] / S_total;   // 512
  int T = in_sizes[1] / D;         // 2048
  int C = in_sizes[3] / T;         // 31

  // workspace layout (4-byte words); zeroed-by-memset region first (~12.4KB)
  int* ws = (int*)d_ws;
  int* pc       = ws;                               // 3*CMAX*PCW padded lines
  float* losssum = (float*)(ws + 3 * CMAX * PCW);   // C
  int* done     = (int*)(losssum + C);              // 8
  int zwords    = 3 * CMAX * PCW + C + 8;

  float* sqc    = (float*)(ws + zwords);            // C*RCAP
  float* sgnc   = sqc + (size_t)C * RCAP;           // C*RCAP
  size_t words_used = (size_t)zwords + 2 * (size_t)C * RCAP;
  size_t fw = (words_used + 63) & ~(size_t)63;      // 256B-align fragbuf
  unsigned short* fragbuf = (unsigned short*)(ws + fw);  // C*RCAP*D bf16

  hipMemsetAsync(d_ws, 0, (size_t)zwords * sizeof(int), stream);

  k_fused<<<1024, 256, 0, stream>>>(source, target, slab, tlabel, nsd_p,
                                    pc, fragbuf, sqc, sgnc,
                                    S_total, T, D, C);
  k_pairs<<<dim3(C, PAIR_Y), 256, 0, stream>>>(fragbuf, sqc, sgnc, pc,
                                               losssum, done, out, D, C);
}

// Round 4
// 86.694 us; speedup vs baseline: 1.2126x; 1.1034x over previous
//
#include <hip/hip_runtime.h>

// MMD loss, class-compacted (r17). 3 nodes: memset(~4.5KB), k_fused, k_pairs.
// r17 change vs r16 (95.7us): ns panel-re-read phase ELIMINATED via the
// identity ns = ||sum x||^2 = sum_{j,k} G[j,k] = what the MFMA tiles already
// compute (same wgt 1/2 + valid-mask structure as the loss epilogue).
// k_pairs is now ONE 1024-thread block per class (16 waves): phase A does
// each tile's MFMA once keeping acc in registers (<=2 tiles/wave for
// tiles<=32; recompute fallback beyond), LDS-reduces wgt*sum(valid acc) ->
// bw; phase B runs the exp epilogue on the SAVED accs. Block-internal sync
// only (r15 lesson: no cross-block publish). Cascade: k_pairs scans
// sqc/sgnc once per class for ss + src/tgt presence -> k_fused tail loses
// the ssum float atomic + flag volatile/atomicExch (~8K RMWs); only the
// rank atomic remains. Per-class loss single-writer atomicExch; 31-block
// done-counter fold.
// NOTE: top-5 rocprof dispatches are the harness's fixed 256MiB workspace
// poison fills (41.7us @81% HBM peak) - NOT controllable from kernel source.
// DO NOT reintroduce: r9 persistent grid-barrier (434us); r5 per-element
// colsum atomics (34MB writes); r2 per-block fences at 6144 grid; r12
// unpadded per-row atomics (54us k_fused); r13 shared rank/ssum/flag line;
// r13 per-block 31-class serial prefix scan; r15 cross-block inv0
// publish/spin (+5.2us); r14/r16 separate ns panel-read phase.
// Math verified absmax 0.0 r1-r16: class bucketing, upper-tri tiles w/ 2x
// off-diag, m@D@m = 2n*sum(sq)-2*||sum x||^2, MFMA C/D map col=lane&31,
// row=(reg&3)+8*(reg>>2)+4*(lane>>5). Panel layout: class c base c*RCAP
// rows; 32-row panels; chunk m (cols m*8..m*8+7) of row i at
// panel*D + (m>>1)*512 + ((m&1)*32 + (i&31))*8. Poisoned pad rows only ever
// land in masked acc entries (each acc[r] is an independent dot product).

#define CMAX 32
#define RCAP 6144      // fixed rows per class region (worst case N=6144)
#define PCW 32         // ints per padded counter line (128B)
#define KP_THREADS 1024
#define KP_WAVES 16

typedef __attribute__((ext_vector_type(8)))  short  short8;
typedef __attribute__((ext_vector_type(8)))  unsigned short ushort8;
typedef __attribute__((ext_vector_type(16))) float  float16;

__device__ inline unsigned short f2bf(float x) {  // fp32 -> bf16 RNE
  unsigned u = __float_as_uint(x);
  return (unsigned short)((u + 0x7FFFu + ((u >> 16) & 1u)) >> 16);
}

// ---- K1: wave-per-row single pass: label + rank + sq + bf16 panel write ----
// pc[c*PCW] = rank counter (one 128B line per class). Tail: plain stores of
// sq and sign only (ss + presence derived in k_pairs from these).
__global__ __launch_bounds__(256) void k_fused(
    const float* __restrict__ src, const float* __restrict__ tgt,
    const int* __restrict__ slab, const float* __restrict__ tlabel,
    const int* __restrict__ nsd_p,
    int* pc,
    unsigned short* __restrict__ fragbuf,
    float* __restrict__ sqc, float* __restrict__ sgnc,
    int S_total, int T, int D, int C) {
  int lane = threadIdx.x & 63;
  int gwid = (blockIdx.x * 256 + threadIdx.x) >> 6;
  int nwv = (gridDim.x * 256) >> 6;
  int nsd = nsd_p[0];
  int S_use = S_total - nsd;
  int N = S_use + T;

  for (int r = gwid; r < N; r += nwv) {
    int c;
    const float* row;
    bool isSrc = (r < S_use);
    if (isSrc) {
      c = slab[nsd + r];
      row = src + (size_t)(nsd + r) * D;
    } else {
      int t = r - S_use;
      row = tgt + (size_t)t * D;
      float v = (lane < C) ? tlabel[(size_t)t * C + lane] : -3.4e38f;
      int idx = lane;
      for (int o = 16; o > 0; o >>= 1) {   // values only in lanes 0..30
        float ov = __shfl_down(v, o, 64);
        int oi = __shfl_down(idx, o, 64);
        if (ov > v || (ov == v && oi < idx)) { v = ov; idx = oi; }
      }
      c = __shfl(idx, 0, 64);
    }
    const float4* s4 = (const float4*)row;
    int nm = D >> 3;
    float4 v0, v1;
    if (lane < nm) { v0 = s4[lane * 2]; v1 = s4[lane * 2 + 1]; }  // in flight

    int rk;
    if (lane == 0) rk = atomicAdd(&pc[c * PCW], 1);   // own 128B line/class
    rk = __shfl(rk, 0, 64);
    int p = c * RCAP + rk;
    unsigned short* pb = fragbuf + (size_t)(c * RCAP + (rk & ~31)) * D;
    int row32 = rk & 31;

    float s = 0.f;
    if (lane < nm) {
      s += v0.x * v0.x + v0.y * v0.y + v0.z * v0.z + v0.w * v0.w +
           v1.x * v1.x + v1.y * v1.y + v1.z * v1.z + v1.w * v1.w;
      ushort8 h;
      h[0] = f2bf(v0.x); h[1] = f2bf(v0.y); h[2] = f2bf(v0.z); h[3] = f2bf(v0.w);
      h[4] = f2bf(v1.x); h[5] = f2bf(v1.y); h[6] = f2bf(v1.z); h[7] = f2bf(v1.w);
      int st = lane >> 1, hf = lane & 1;
      *(ushort8*)(pb + st * 512 + (hf * 32 + row32) * 8) = h;
    }
    for (int m = lane + 64; m < nm; m += 64) {   // D>512 fallback (not hit)
      float4 w0 = s4[m * 2], w1 = s4[m * 2 + 1];
      s += w0.x * w0.x + w0.y * w0.y + w0.z * w0.z + w0.w * w0.w +
           w1.x * w1.x + w1.y * w1.y + w1.z * w1.z + w1.w * w1.w;
      ushort8 h;
      h[0] = f2bf(w0.x); h[1] = f2bf(w0.y); h[2] = f2bf(w0.z); h[3] = f2bf(w0.w);
      h[4] = f2bf(w1.x); h[5] = f2bf(w1.y); h[6] = f2bf(w1.z); h[7] = f2bf(w1.w);
      int st = m >> 1, hf = m & 1;
      *(ushort8*)(pb + st * 512 + (hf * 32 + row32) * 8) = h;
    }
    for (int o = 32; o > 0; o >>= 1) s += __shfl_down(s, o, 64);
    if (lane == 0) {
      sqc[p] = s;
      sgnc[p] = isSrc ? 1.f : -1.f;
    }
  }
}

// ---- K2 helpers ----
__device__ inline void tile_decode(int t, int tpr, int& jbase, int& kbase,
                                   float& wgt) {
  int lt = t, jt = 0;
  while (lt >= tpr - jt) { lt -= tpr - jt; jt++; }
  int kt = jt + lt;
  jbase = jt << 5; kbase = kt << 5;
  wgt = (jt == kt) ? 1.f : 2.f;
}

__device__ inline float16 tile_mfma(const unsigned short* __restrict__ fragbuf,
                                    int off, int D, int jbase, int kbase,
                                    int lane) {
  const unsigned short* fa = fragbuf + (size_t)(off + jbase) * D + lane * 8;
  const unsigned short* fb = fragbuf + (size_t)(off + kbase) * D + lane * 8;
  float16 acc = {};
  if (D == 512) {
    #pragma unroll
    for (int s = 0; s < 32; s++) {
      short8 a = *(const short8*)(fa + s * 512);
      short8 b = *(const short8*)(fb + s * 512);
      acc = __builtin_amdgcn_mfma_f32_32x32x16_bf16(a, b, acc, 0, 0, 0);
    }
  } else {
    for (int s = 0; s < (D >> 4); s++) {
      short8 a = *(const short8*)(fa + s * 512);
      short8 b = *(const short8*)(fb + s * 512);
      acc = __builtin_amdgcn_mfma_f32_32x32x16_bf16(a, b, acc, 0, 0, 0);
    }
  }
  return acc;
}

// ns contribution of this tile: wgt * sum over valid (j,k) of G[j,k]
__device__ inline float ns_part(const float16& acc, int jbase, int kbase,
                                int n, int l31, int half, float wgt) {
  if ((kbase + l31) >= n) return 0.f;
  float ps = 0.f;
  #pragma unroll
  for (int r = 0; r < 16; r++) {
    int m = (r & 3) + 8 * (r >> 2) + 4 * half;
    if ((jbase + m) < n) ps += acc[r];
  }
  return wgt * ps;
}

__device__ inline float tile_contrib(const float16& acc,
                                     const float* __restrict__ sqc,
                                     const float* __restrict__ sgnc,
                                     int off, int jbase, int kbase, int n,
                                     int l31, int half, float wgt, float inv0) {
  float sqk  = sqc[off + kbase + l31];
  float sgk  = sgnc[off + kbase + l31];
  float sqjv = sqc[off + jbase + l31];
  float sgjv = sgnc[off + jbase + l31];
  bool kval = (kbase + l31) < n;
  float contrib = 0.f;
  #pragma unroll
  for (int r = 0; r < 16; r++) {
    int m = (r & 3) + 8 * (r >> 2) + 4 * half;
    float sqj = __shfl(sqjv, m, 64);
    float sgj = __shfl(sgjv, m, 64);
    if (kval && (jbase + m) < n) {
      float d = fmaxf(sqj + sqk - 2.f * acc[r], 0.f);
      float s = inv0, kv = 0.f;
      #pragma unroll
      for (int q = 0; q < 5; q++) { kv += __expf(-d * s); s *= 0.5f; }
      contrib += sgj * sgk * kv;
    }
  }
  return wgt * contrib;
}

// ---- K2: one block per class. Phase A: all tiles' MFMA (accs kept in regs,
// <=2/wave when tiles<=32) + ns partials; LDS reduce -> bw; Phase B: exp
// epilogue on saved accs. ss + presence flags from a one-shot sqc/sgnc scan.
__global__ __launch_bounds__(KP_THREADS) void k_pairs(
    const unsigned short* __restrict__ fragbuf, const float* __restrict__ sqc,
    const float* __restrict__ sgnc, const int* __restrict__ pc,
    float* losssum, float* glb /*[0]=cv acc, [1]=done(int)*/,
    float* __restrict__ out, int D, int C) {
  __shared__ float s_ns[KP_WAVES], s_ss[KP_WAVES], s_ws[KP_WAVES];
  __shared__ float s_inv0;
  __shared__ int s_flag[2];
  __shared__ int lastFlag;

  int c = blockIdx.x;
  int tid = threadIdx.x;
  int wv = tid >> 6, lane = tid & 63;
  int l31 = lane & 31, half = lane >> 5;
  int n = pc[c * PCW];
  int off = c * RCAP;

  if (tid < 2) s_flag[tid] = 0;
  __syncthreads();

  // one-shot scan: ss = sum sq, presence flags from sign
  float ssp = 0.f;
  bool anyS = false, anyT = false;
  for (int i = tid; i < n; i += KP_THREADS) {
    ssp += sqc[off + i];
    float g = sgnc[off + i];
    anyS |= (g > 0.f); anyT |= (g < 0.f);
  }
  if (anyS) s_flag[0] = 1;      // plain same-value stores: race-free
  if (anyT) s_flag[1] = 1;
  for (int o = 32; o > 0; o >>= 1) ssp += __shfl_down(ssp, o, 64);
  if (lane == 0) s_ss[wv] = ssp;

  int tpr = (n + 31) >> 5;
  int tiles = tpr * (tpr + 1) / 2;
  bool fast = (tiles <= KP_WAVES * 2);

  // ---- Phase A ----
  float16 accA = {}, accB = {};
  int jbA = 0, kbA = 0, jbB = 0, kbB = 0;
  float wgA = 0.f, wgB = 0.f;
  bool hasA = false, hasB = false;
  float nsp = 0.f;
  if (fast) {
    int tA = wv;
    if (tA < tiles) {
      tile_decode(tA, tpr, jbA, kbA, wgA);
      accA = tile_mfma(fragbuf, off, D, jbA, kbA, lane);
      nsp += ns_part(accA, jbA, kbA, n, l31, half, wgA);
      hasA = true;
    }
    int tB = wv + KP_WAVES;
    if (tB < tiles) {
      tile_decode(tB, tpr, jbB, kbB, wgB);
      accB = tile_mfma(fragbuf, off, D, jbB, kbB, lane);
      nsp += ns_part(accB, jbB, kbB, n, l31, half, wgB);
      hasB = true;
    }
  } else {  // huge-class fallback: ns pass now, recompute MFMA in phase B
    for (int t = wv; t < tiles; t += KP_WAVES) {
      int jb, kb; float wg;
      tile_decode(t, tpr, jb, kb, wg);
      float16 acc = tile_mfma(fragbuf, off, D, jb, kb, lane);
      nsp += ns_part(acc, jb, kb, n, l31, half, wg);
    }
  }
  for (int o = 32; o > 0; o >>= 1) nsp += __shfl_down(nsp, o, 64);
  if (lane == 0) s_ns[wv] = nsp;
  __syncthreads();

  if (tid == 0) {
    float ss = 0.f, ns = 0.f;
    #pragma unroll
    for (int w = 0; w < KP_WAVES; w++) { ss += s_ss[w]; ns += s_ns[w]; }
    float nf = (float)n;
    float S1 = 2.f * nf * ss - 2.f * ns;       // == m @ Dmat @ m
    float bw = S1 / fmaxf(nf * nf - nf, 1.f);
    bw = (bw > 0.f) ? bw : 1.f;
    s_inv0 = 4.f / bw;                          // 1 / (bw * 0.25)
  }
  __syncthreads();
  float inv0 = s_inv0;

  // ---- Phase B ----
  float wsum = 0.f;
  if (fast) {
    if (hasA) wsum += tile_contrib(accA, sqc, sgnc, off, jbA, kbA, n,
                                   l31, half, wgA, inv0);
    if (hasB) wsum += tile_contrib(accB, sqc, sgnc, off, jbB, kbB, n,
                                   l31, half, wgB, inv0);
  } else {
    for (int t = wv; t < tiles; t += KP_WAVES) {
      int jb, kb; float wg;
      tile_decode(t, tpr, jb, kb, wg);
      float16 acc = tile_mfma(fragbuf, off, D, jb, kb, lane);
      wsum += tile_contrib(acc, sqc, sgnc, off, jb, kb, n,
                           l31, half, wg, inv0);
    }
  }
  for (int o = 32; o > 0; o >>= 1) wsum += __shfl_down(wsum, o, 64);
  if (lane == 0) s_ws[wv] = wsum;
  __syncthreads();

  if (tid == 0) {
    float tot = 0.f;
    #pragma unroll
    for (int w = 0; w < KP_WAVES; w++) tot += s_ws[w];
    bool valid = s_flag[0] && s_flag[1];
    float nf = (float)n;
    atomicExch(&losssum[c], valid ? tot / fmaxf(nf * nf, 1.f) : 0.f);
    if (valid) atomicAdd(&glb[0], 1.f);
  }

  // last-block fold -> final scalar
  __syncthreads();
  if (tid == 0) {
    __threadfence();
    int d = atomicAdd((int*)&glb[1], 1);
    lastFlag = (d == C - 1);
  }
  __syncthreads();
  if (lastFlag && tid < 64) {
    int cc = tid;
    float loss = (cc < C) ? atomicAdd(&losssum[cc], 0.f) : 0.f;  // coherent
    for (int o = 32; o > 0; o >>= 1) loss += __shfl_down(loss, o, 64);
    if (tid == 0) {
      float cv = atomicAdd(&glb[0], 0.f);
      out[0] = loss / fmaxf(cv, 1.f);
    }
  }
}

extern "C" void kernel_launch(void* const* d_in, const int* in_sizes, int n_in,
                              void* d_out, int out_size, void* d_ws, size_t ws_size,
                              hipStream_t stream) {
  const float* source = (const float*)d_in[0];
  const float* target = (const float*)d_in[1];
  const int* slab     = (const int*)d_in[2];
  const float* tlabel = (const float*)d_in[3];
  const int* nsd_p    = (const int*)d_in[4];
  float* out = (float*)d_out;

  int S_total = in_sizes[2];
  int D = in_sizes[0] / S_total;   // 512
  int T = in_sizes[1] / D;         // 2048
  int C = in_sizes[3] / T;         // 31

  // workspace layout (4-byte words); zeroed-by-memset region first (~4.5KB)
  int* ws = (int*)d_ws;
  int* pc        = ws;                              // CMAX*PCW rank lines
  float* losssum = (float*)(ws + CMAX * PCW);       // CMAX
  float* glb     = (float*)(ws + CMAX * PCW + CMAX);// 8 words: cv, done
  int zwords     = CMAX * PCW + CMAX + 8;

  float* sqc    = (float*)(ws + zwords);            // C*RCAP
  float* sgnc   = sqc + (size_t)C * RCAP;           // C*RCAP
  size_t words_used = (size_t)zwords + 2 * (size_t)C * RCAP;
  size_t fw = (words_used + 63) & ~(size_t)63;      // 256B-align fragbuf
  unsigned short* fragbuf = (unsigned short*)(ws + fw);  // C*RCAP*D bf16

  hipMemsetAsync(d_ws, 0, (size_t)zwords * sizeof(int), stream);

  k_fused<<<1024, 256, 0, stream>>>(source, target, slab, tlabel, nsd_p,
                                    pc, fragbuf, sqc, sgnc,
                                    S_total, T, D, C);
  k_pairs<<<C, KP_THREADS, 0, stream>>>(fragbuf, sqc, sgnc, pc,
                                        losssum, glb, out, D, C);
}